// Round 12
// baseline (208.336 us; speedup 1.0000x reference)
//
#include <hip/hip_runtime.h>
#include <hip/hip_bf16.h>

typedef __hip_bfloat16 bf16;
typedef float f32x2 __attribute__((ext_vector_type(2)));

#define L_AG 5
#define C_CH 16
#define H_SZ 256
#define W_SZ 256
#define HW_SZ (H_SZ * W_SZ)

// dtype-polymorphic load/store helpers
__device__ __forceinline__ float ldf(const float* p) { return *p; }
__device__ __forceinline__ float ldf(const bf16* p)  { return __bfloat162float(*p); }
__device__ __forceinline__ void  stf(float* p, float v) { *p = v; }
__device__ __forceinline__ void  stf(bf16* p, float v)  { *p = __float2bfloat16(v); }

__device__ __forceinline__ f32x2 pk_fma(f32x2 a, f32x2 b, f32x2 c) {
    return __builtin_elementwise_fma(a, b, c);   // -> v_pk_fma_f32
}
__device__ __forceinline__ f32x2 pk_relu(f32x2 a) {
    return __builtin_elementwise_max(a, (f32x2){0.0f, 0.0f});  // -> v_pk_max_f32
}

// Runtime dtype detector: looks at even-indexed uint16 words of x.
// bf16 ~N(0,1): exponent field < 0x90 always (|v| >= 2^17 impossible).
// fp32 read as words: even words = random mantissa bits -> ~43% have exp >= 0x90.
__global__ void dtype_detect(const unsigned short* __restrict__ xw, int* __restrict__ flag) {
    __shared__ int cnt;
    if (threadIdx.x == 0) cnt = 0;
    __syncthreads();
    int h = 0;
    for (int t = threadIdx.x; t < 512; t += 256) {
        const unsigned short w = xw[2 * t];
        const int e = (w >> 7) & 0xFF;
        h += (e >= 0x90) ? 1 : 0;
    }
    atomicAdd(&cnt, h);
    __syncthreads();
    if (threadIdx.x == 0) flag[0] = (cnt >= 16) ? 1 : 0;  // 1 = fp32, 0 = bf16
}

// Inverse-affine taps for neighbor j as pair offsets (po0: row y0, po1: row
// y1, both at column base cx0p=min(cx0,W-2); the partner element is po+1)
// plus remapped bilinear weights (aw*lo + bw*hi per row). Exactly reproduces
// clamp+validity semantics.
__device__ __forceinline__ void tap_params(
    const float (*minv)[6], int j, float px, float py,
    int& po0, int& po1, float& aw0, float& bw0, float& aw1, float& bw1)
{
    const float m0 = minv[j][0], m1 = minv[j][1], m2 = minv[j][2];
    const float m3 = minv[j][3], m4 = minv[j][4], m5 = minv[j][5];
    const float sx = m0 * px + m1 * py + m2;
    const float sy = m3 * px + m4 * py + m5;
    const float fx0 = floorf(sx), fy0 = floorf(sy);
    const int x0 = (int)fx0, y0 = (int)fy0;
    const float wx1 = sx - fx0, wy1 = sy - fy0;
    const float wx0 = 1.0f - wx1, wy0 = 1.0f - wy1;
    const bool vx0 = (x0 >= 0) && (x0 <= W_SZ - 1);
    const bool vx1 = (x0 + 1 >= 0) && (x0 + 1 <= W_SZ - 1);
    const bool vy0 = (y0 >= 0) && (y0 <= H_SZ - 1);
    const bool vy1 = (y0 + 1 >= 0) && (y0 + 1 <= H_SZ - 1);
    const float w00 = (vx0 && vy0) ? wx0 * wy0 : 0.0f;
    const float w01 = (vx1 && vy0) ? wx1 * wy0 : 0.0f;
    const float w10 = (vx0 && vy1) ? wx0 * wy1 : 0.0f;
    const float w11 = (vx1 && vy1) ? wx1 * wy1 : 0.0f;
    const int cx0 = min(max(x0, 0), W_SZ - 1);
    const int cx1 = min(max(x0 + 1, 0), W_SZ - 1);
    const int cy0 = min(max(y0, 0), H_SZ - 1);
    const int cy1 = min(max(y0 + 1, 0), H_SZ - 1);
    const int cx0p = min(cx0, W_SZ - 2);
    const bool l0 = (cx0 == cx0p);   // does cx0 sit in the LO slot?
    const bool l1 = (cx1 == cx0p);   // does cx1 sit in the LO slot?
    aw0 = (l0 ? w00 : 0.0f) + (l1 ? w01 : 0.0f);
    bw0 = (l0 ? 0.0f : w00) + (l1 ? 0.0f : w01);
    aw1 = (l0 ? w10 : 0.0f) + (l1 ? w11 : 0.0f);
    bw1 = (l0 ? 0.0f : w10) + (l1 ? 0.0f : w11);
    po0 = cy0 * W_SZ + cx0p;
    po1 = cy1 * W_SZ + cx0p;
}

// (256,8): cap 64 VGPR. R11 measured true demand = 56 with the fenced
// row-phased body (WRITE exactly 20.5MB = zero spill). At cap 64 the ENTIRE
// 1280-block grid is co-resident (5 blocks/CU, 20 waves/CU) — no ramp, no
// tail, which is what held R11 at 28% occupancy under the promise-4 cap.
// Spill signature to watch: VGPR=64 + WRITE >> 100MB -> revert to promise 4.
template <typename T, typename OT>
__global__ __launch_bounds__(256, 8) void disconet_fused(
    const T* __restrict__ x, const T* __restrict__ ptm,
    const T* __restrict__ w1, const T* __restrict__ b1,
    const T* __restrict__ g1, const T* __restrict__ be1,
    const T* __restrict__ rm1, const T* __restrict__ rv1,
    const T* __restrict__ w2, const T* __restrict__ b2,
    const T* __restrict__ g2, const T* __restrict__ be2,
    const T* __restrict__ rm2, const T* __restrict__ rv2,
    const T* __restrict__ w3, const T* __restrict__ b3,
    const T* __restrict__ g3, const T* __restrict__ be3,
    const T* __restrict__ rm3, const T* __restrict__ rv3,
    const T* __restrict__ w4, const T* __restrict__ b4,
    const T* __restrict__ wm, const T* __restrict__ bm,
    OT* __restrict__ out, const int* __restrict__ flag, const int want)
{
    if (flag[0] != want) return;   // wave-uniform path select

    // Weights pre-packed for v_pk_fma_f32: wpk[cin][o2] = {w[2o2][cin]*s,
    // w[2o2+1][cin]*s'} -> broadcast input scalar, accumulate output PAIRS.
    __shared__ __align__(16) f32x2 s_w1p[32][8];   // cin 0..15 nb | 16..31 ego
    __shared__ __align__(16) float s_b1[16];
    __shared__ __align__(16) f32x2 s_w2p[16][4];
    __shared__ __align__(16) float s_b2[8];
    __shared__ __align__(16) f32x2 s_w3p[8][2];
    __shared__ __align__(16) float s_b3[4];
    __shared__ __align__(16) float s_w4v[4];
    __shared__ float s_b4;
    __shared__ __align__(16) f32x2 s_wmp[16][8];
    __shared__ __align__(16) float s_bm[16];
    __shared__ float s_minv[L_AG][6];

    const int tid = threadIdx.x;

    // ---- block -> (ego, 2D tile), XCD-column + EGO-INNERMOST ordering ----
    const int bid      = blockIdx.x;
    const int tile_col = bid & 7;
    const int bp       = bid >> 3;        // 0..159
    const int i        = bp % L_AG;       // ego (inner)
    const int tile_row = bp / L_AG;       // 0..31 (outer)

    const int px_i = (tile_col << 5) + (tid & 31);   // 32x8 tile, coalesced rows
    const int py_i = (tile_row << 3) + (tid >> 5);
    const int p    = py_i * W_SZ + px_i;

    // ---- cooperative init: fold BN into conv weights, pack output-pairs ----
    {   // s_w1p: 32*8 = 256 entries, one per thread
        const int cin = tid >> 3, o2 = tid & 7;
        const int oa = 2 * o2, ob = 2 * o2 + 1;
        const float sa = ldf(g1 + oa) * rsqrtf(ldf(rv1 + oa) + 1e-5f);
        const float sb = ldf(g1 + ob) * rsqrtf(ldf(rv1 + ob) + 1e-5f);
        s_w1p[cin][o2] = (f32x2){ ldf(w1 + oa * 32 + cin) * sa,
                                  ldf(w1 + ob * 32 + cin) * sb };
    }
    if (tid < 64) {   // s_w2p: 16*4
        const int cin = tid >> 2, o2 = tid & 3;
        const int oa = 2 * o2, ob = 2 * o2 + 1;
        const float sa = ldf(g2 + oa) * rsqrtf(ldf(rv2 + oa) + 1e-5f);
        const float sb = ldf(g2 + ob) * rsqrtf(ldf(rv2 + ob) + 1e-5f);
        s_w2p[cin][o2] = (f32x2){ ldf(w2 + oa * 16 + cin) * sa,
                                  ldf(w2 + ob * 16 + cin) * sb };
    }
    if (tid < 16) {   // s_w3p: 8*2
        const int cin = tid >> 1, o2 = tid & 1;
        const int oa = 2 * o2, ob = 2 * o2 + 1;
        const float sa = ldf(g3 + oa) * rsqrtf(ldf(rv3 + oa) + 1e-5f);
        const float sb = ldf(g3 + ob) * rsqrtf(ldf(rv3 + ob) + 1e-5f);
        s_w3p[cin][o2] = (f32x2){ ldf(w3 + oa * 8 + cin) * sa,
                                  ldf(w3 + ob * 8 + cin) * sb };
    }
    if (tid >= 128 && tid < 256) {   // s_wmp: 16*8 (no BN fold)
        const int t = tid - 128;
        const int cin = t >> 3, o2 = t & 7;
        s_wmp[cin][o2] = (f32x2){ ldf(wm + (2 * o2) * 16 + cin),
                                  ldf(wm + (2 * o2 + 1) * 16 + cin) };
    }
    if (tid < 16) {
        const float s1 = ldf(g1 + tid) * rsqrtf(ldf(rv1 + tid) + 1e-5f);
        s_b1[tid] = (ldf(b1 + tid) - ldf(rm1 + tid)) * s1 + ldf(be1 + tid);
        s_bm[tid] = ldf(bm + tid);
    }
    if (tid < 8) {
        const float s2 = ldf(g2 + tid) * rsqrtf(ldf(rv2 + tid) + 1e-5f);
        s_b2[tid] = (ldf(b2 + tid) - ldf(rm2 + tid)) * s2 + ldf(be2 + tid);
    }
    if (tid < 4) {
        const float s3 = ldf(g3 + tid) * rsqrtf(ldf(rv3 + tid) + 1e-5f);
        s_b3[tid] = (ldf(b3 + tid) - ldf(rm3 + tid)) * s3 + ldf(be3 + tid);
        s_w4v[tid] = ldf(w4 + tid);
    }
    if (tid == 0) s_b4 = ldf(b4);

    if (tid < L_AG) {
        const int j = tid;
        const T* m = ptm + (j * L_AG + i) * 16;  // (1,L,L,4,4) row-major
        const float a  = ldf(m + 0);
        const float bb = ldf(m + 1);
        const float tx = ldf(m + 3) * 1.25f;     // / (0.4*2)
        const float c_ = ldf(m + 4);
        const float d  = ldf(m + 5);
        const float ty = ldf(m + 7) * 1.25f;
        float det = a * d - bb * c_;
        if (!(det > 1e-20f || det < -1e-20f)) det = 1.0f;  // guard: never Inf
        const float invdet = 1.0f / det;
        s_minv[j][0] =  d * invdet;
        s_minv[j][1] = -bb * invdet;
        s_minv[j][2] = (bb * ty - d * tx) * invdet;
        s_minv[j][3] = -c_ * invdet;
        s_minv[j][4] =  a * invdet;
        s_minv[j][5] = (c_ * tx - a * ty) * invdet;
    }
    __syncthreads();

    const float px = (float)px_i;
    const float py = (float)py_i;

    // ego contribution to layer 1 is j-invariant: hoist it (packed pairs).
    f32x2 h1bv[8];
#pragma unroll
    for (int o2 = 0; o2 < 8; ++o2)
        h1bv[o2] = *reinterpret_cast<const f32x2*>(&s_b1[2 * o2]);
    {
        const T* xp = x + i * C_CH * HW_SZ + p;
#pragma unroll
        for (int c = 0; c < C_CH; ++c) {
            const float e = ldf(xp + c * HW_SZ);
            const f32x2 bc = (f32x2){e, e};
#pragma unroll
            for (int o2 = 0; o2 < 8; ++o2)
                h1bv[o2] = pk_fma(s_w1p[16 + c][o2], bc, h1bv[o2]);
        }
    }

    float acc[C_CH];
#pragma unroll
    for (int c = 0; c < C_CH; ++c) acc[c] = 0.0f;
    float lsum = 0.0f;

    // ---- j-loop: serial row-phased taps (max 32 regs in flight), every
    // phase PINNED with sched_barrier(0) so the pre-RA scheduler cannot
    // hoist loads and inflate the live set past the cap (R9's bug). ----
#pragma unroll 1
    for (int j = 0; j < L_AG; ++j) {
        int po0, po1;
        float aw0, bw0, aw1, bw1;
        tap_params(s_minv, j, px, py, po0, po1, aw0, bw0, aw1, bw1);
        const T* img = x + j * C_CH * HW_SZ;

        float nb[C_CH];
        __builtin_amdgcn_sched_barrier(0);
        {   // phase 1: row y0 (16 addr-pairs fold +1 into offset imm)
            float tl[C_CH], th[C_CH];
#pragma unroll
            for (int c = 0; c < C_CH; ++c) {
                const T* ic = img + c * HW_SZ;
                tl[c] = ldf(ic + po0); th[c] = ldf(ic + po0 + 1);
            }
#pragma unroll
            for (int c = 0; c < C_CH; ++c) nb[c] = aw0 * tl[c] + bw0 * th[c];
        }
        __builtin_amdgcn_sched_barrier(0);
        {   // phase 2: row y1
            float tl[C_CH], th[C_CH];
#pragma unroll
            for (int c = 0; c < C_CH; ++c) {
                const T* ic = img + c * HW_SZ;
                tl[c] = ldf(ic + po1); th[c] = ldf(ic + po1 + 1);
            }
#pragma unroll
            for (int c = 0; c < C_CH; ++c) nb[c] += aw1 * tl[c] + bw1 * th[c];
        }
        __builtin_amdgcn_sched_barrier(0);

        // MLP 32->16->8->4->1, packed output-pairs (v_pk_fma_f32);
        // ego half of layer 1 precomputed in h1bv.
        f32x2 h1v[8];
#pragma unroll
        for (int o2 = 0; o2 < 8; ++o2) h1v[o2] = h1bv[o2];
#pragma unroll
        for (int c = 0; c < C_CH; ++c) {
            const f32x2 bc = (f32x2){nb[c], nb[c]};
#pragma unroll
            for (int o2 = 0; o2 < 8; ++o2)
                h1v[o2] = pk_fma(s_w1p[c][o2], bc, h1v[o2]);
        }
#pragma unroll
        for (int o2 = 0; o2 < 8; ++o2) h1v[o2] = pk_relu(h1v[o2]);

        f32x2 h2v[4];
#pragma unroll
        for (int o2 = 0; o2 < 4; ++o2)
            h2v[o2] = *reinterpret_cast<const f32x2*>(&s_b2[2 * o2]);
#pragma unroll
        for (int c = 0; c < 16; ++c) {
            const float hs = (c & 1) ? h1v[c >> 1].y : h1v[c >> 1].x;
            const f32x2 bc = (f32x2){hs, hs};
#pragma unroll
            for (int o2 = 0; o2 < 4; ++o2)
                h2v[o2] = pk_fma(s_w2p[c][o2], bc, h2v[o2]);
        }
#pragma unroll
        for (int o2 = 0; o2 < 4; ++o2) h2v[o2] = pk_relu(h2v[o2]);

        f32x2 h3v[2];
#pragma unroll
        for (int o2 = 0; o2 < 2; ++o2)
            h3v[o2] = *reinterpret_cast<const f32x2*>(&s_b3[2 * o2]);
#pragma unroll
        for (int c = 0; c < 8; ++c) {
            const float hs = (c & 1) ? h2v[c >> 1].y : h2v[c >> 1].x;
            const f32x2 bc = (f32x2){hs, hs};
#pragma unroll
            for (int o2 = 0; o2 < 2; ++o2)
                h3v[o2] = pk_fma(s_w3p[c][o2], bc, h3v[o2]);
        }
        h3v[0] = pk_relu(h3v[0]); h3v[1] = pk_relu(h3v[1]);

        float sc = s_b4 + s_w4v[0] * h3v[0].x + s_w4v[1] * h3v[0].y
                        + s_w4v[2] * h3v[1].x + s_w4v[3] * h3v[1].y;
        sc = fminf(fmaxf(sc, 0.0f), 60.0f);  // relu + overflow guard

        const float es = __expf(sc);
        lsum += es;
#pragma unroll
        for (int c = 0; c < C_CH; ++c) acc[c] += es * nb[c];
    }

    const float invl = 1.0f / lsum;
#pragma unroll
    for (int c = 0; c < C_CH; ++c) acc[c] *= invl;

    // epilogue: 16x16 mix, packed output-pairs
    f32x2 outv[8];
#pragma unroll
    for (int o2 = 0; o2 < 8; ++o2)
        outv[o2] = *reinterpret_cast<const f32x2*>(&s_bm[2 * o2]);
#pragma unroll
    for (int c = 0; c < C_CH; ++c) {
        const f32x2 bc = (f32x2){acc[c], acc[c]};
#pragma unroll
        for (int o2 = 0; o2 < 8; ++o2)
            outv[o2] = pk_fma(s_wmp[c][o2], bc, outv[o2]);
    }
    OT* op = out + i * C_CH * HW_SZ + p;
#pragma unroll
    for (int o2 = 0; o2 < 8; ++o2) {
        stf(op + (2 * o2) * HW_SZ,     outv[o2].x);
        stf(op + (2 * o2 + 1) * HW_SZ, outv[o2].y);
    }
}

extern "C" void kernel_launch(void* const* d_in, const int* in_sizes, int n_in,
                              void* d_out, int out_size, void* d_ws, size_t ws_size,
                              hipStream_t stream) {
    int* flag = (int*)d_ws;
    dtype_detect<<<1, 256, 0, stream>>>((const unsigned short*)d_in[0], flag);

    // 1280 blocks: 8 tile-cols x (5 egos inner x 32 tile-rows)
    dim3 grid(8 * 32 * L_AG);

    // bf16 path (flag==0)
    disconet_fused<bf16, bf16><<<grid, 256, 0, stream>>>(
        (const bf16*)d_in[0], (const bf16*)d_in[2],
        (const bf16*)d_in[3], (const bf16*)d_in[4],
        (const bf16*)d_in[5], (const bf16*)d_in[6],
        (const bf16*)d_in[7], (const bf16*)d_in[8],
        (const bf16*)d_in[9], (const bf16*)d_in[10],
        (const bf16*)d_in[11], (const bf16*)d_in[12],
        (const bf16*)d_in[13], (const bf16*)d_in[14],
        (const bf16*)d_in[15], (const bf16*)d_in[16],
        (const bf16*)d_in[17], (const bf16*)d_in[18],
        (const bf16*)d_in[19], (const bf16*)d_in[20],
        (const bf16*)d_in[21], (const bf16*)d_in[22],
        (const bf16*)d_in[23], (const bf16*)d_in[24],
        (bf16*)d_out, flag, 0);

    // fp32 path (flag==1)
    disconet_fused<float, float><<<grid, 256, 0, stream>>>(
        (const float*)d_in[0], (const float*)d_in[2],
        (const float*)d_in[3], (const float*)d_in[4],
        (const float*)d_in[5], (const float*)d_in[6],
        (const float*)d_in[7], (const float*)d_in[8],
        (const float*)d_in[9], (const float*)d_in[10],
        (const float*)d_in[11], (const float*)d_in[12],
        (const float*)d_in[13], (const float*)d_in[14],
        (const float*)d_in[15], (const float*)d_in[16],
        (const float*)d_in[17], (const float*)d_in[18],
        (const float*)d_in[19], (const float*)d_in[20],
        (const float*)d_in[21], (const float*)d_in[22],
        (const float*)d_in[23], (const float*)d_in[24],
        (float*)d_out, flag, 1);
}

// Round 13
// 171.048 us; speedup vs baseline: 1.2180x; 1.2180x over previous
//
#include <hip/hip_runtime.h>
#include <hip/hip_bf16.h>

typedef __hip_bfloat16 bf16;
typedef float f32x2 __attribute__((ext_vector_type(2)));

#define L_AG 5
#define C_CH 16
#define H_SZ 256
#define W_SZ 256
#define HW_SZ (H_SZ * W_SZ)

// dtype-polymorphic load/store helpers
__device__ __forceinline__ float ldf(const float* p) { return *p; }
__device__ __forceinline__ float ldf(const bf16* p)  { return __bfloat162float(*p); }
__device__ __forceinline__ void  stf(float* p, float v) { *p = v; }
__device__ __forceinline__ void  stf(bf16* p, float v)  { *p = __float2bfloat16(v); }

__device__ __forceinline__ f32x2 pk_fma(f32x2 a, f32x2 b, f32x2 c) {
    return __builtin_elementwise_fma(a, b, c);   // -> v_pk_fma_f32
}
__device__ __forceinline__ f32x2 pk_relu(f32x2 a) {
    return __builtin_elementwise_max(a, (f32x2){0.0f, 0.0f});  // -> v_pk_max_f32
}

// Runtime dtype detector: looks at even-indexed uint16 words of x.
// bf16 ~N(0,1): exponent field < 0x90 always (|v| >= 2^17 impossible).
// fp32 read as words: even words = random mantissa bits -> ~43% have exp >= 0x90.
__global__ void dtype_detect(const unsigned short* __restrict__ xw, int* __restrict__ flag) {
    __shared__ int cnt;
    if (threadIdx.x == 0) cnt = 0;
    __syncthreads();
    int h = 0;
    for (int t = threadIdx.x; t < 512; t += 256) {
        const unsigned short w = xw[2 * t];
        const int e = (w >> 7) & 0xFF;
        h += (e >= 0x90) ? 1 : 0;
    }
    atomicAdd(&cnt, h);
    __syncthreads();
    if (threadIdx.x == 0) flag[0] = (cnt >= 16) ? 1 : 0;  // 1 = fp32, 0 = bf16
}

// Inverse-affine taps for neighbor j as pair offsets (po0: row y0, po1: row
// y1, both at column base cx0p=min(cx0,W-2); the partner element is po+1)
// plus remapped bilinear weights (aw*lo + bw*hi per row). Exactly reproduces
// clamp+validity semantics.
__device__ __forceinline__ void tap_params(
    const float (*minv)[6], int j, float px, float py,
    int& po0, int& po1, float& aw0, float& bw0, float& aw1, float& bw1)
{
    const float m0 = minv[j][0], m1 = minv[j][1], m2 = minv[j][2];
    const float m3 = minv[j][3], m4 = minv[j][4], m5 = minv[j][5];
    const float sx = m0 * px + m1 * py + m2;
    const float sy = m3 * px + m4 * py + m5;
    const float fx0 = floorf(sx), fy0 = floorf(sy);
    const int x0 = (int)fx0, y0 = (int)fy0;
    const float wx1 = sx - fx0, wy1 = sy - fy0;
    const float wx0 = 1.0f - wx1, wy0 = 1.0f - wy1;
    const bool vx0 = (x0 >= 0) && (x0 <= W_SZ - 1);
    const bool vx1 = (x0 + 1 >= 0) && (x0 + 1 <= W_SZ - 1);
    const bool vy0 = (y0 >= 0) && (y0 <= H_SZ - 1);
    const bool vy1 = (y0 + 1 >= 0) && (y0 + 1 <= H_SZ - 1);
    const float w00 = (vx0 && vy0) ? wx0 * wy0 : 0.0f;
    const float w01 = (vx1 && vy0) ? wx1 * wy0 : 0.0f;
    const float w10 = (vx0 && vy1) ? wx0 * wy1 : 0.0f;
    const float w11 = (vx1 && vy1) ? wx1 * wy1 : 0.0f;
    const int cx0 = min(max(x0, 0), W_SZ - 1);
    const int cx1 = min(max(x0 + 1, 0), W_SZ - 1);
    const int cy0 = min(max(y0, 0), H_SZ - 1);
    const int cy1 = min(max(y0 + 1, 0), H_SZ - 1);
    const int cx0p = min(cx0, W_SZ - 2);
    const bool l0 = (cx0 == cx0p);   // does cx0 sit in the LO slot?
    const bool l1 = (cx1 == cx0p);   // does cx1 sit in the LO slot?
    aw0 = (l0 ? w00 : 0.0f) + (l1 ? w01 : 0.0f);
    bw0 = (l0 ? 0.0f : w00) + (l1 ? 0.0f : w01);
    aw1 = (l0 ? w10 : 0.0f) + (l1 ? w11 : 0.0f);
    bw1 = (l0 ? 0.0f : w10) + (l1 ? 0.0f : w11);
    po0 = cy0 * W_SZ + cx0p;
    po1 = cy1 * W_SZ + cx0p;
}

// (256,5): cap ~102 VGPR, 5 blocks/CU — exactly the whole 1280-block grid
// co-resident (grid offers 1280/256 = 5 blocks/CU; promise 8 bought nothing
// more and its 64-cap spilled: R12 VGPR=32, WRITE 148MB). Demand measured 56
// (R11, zero spill) -> cap 102 leaves 1.8x headroom. Occupancy target ~48%
// (R12 proved the residency), at R11's zero-spill efficiency.
template <typename T, typename OT>
__global__ __launch_bounds__(256, 5) void disconet_fused(
    const T* __restrict__ x, const T* __restrict__ ptm,
    const T* __restrict__ w1, const T* __restrict__ b1,
    const T* __restrict__ g1, const T* __restrict__ be1,
    const T* __restrict__ rm1, const T* __restrict__ rv1,
    const T* __restrict__ w2, const T* __restrict__ b2,
    const T* __restrict__ g2, const T* __restrict__ be2,
    const T* __restrict__ rm2, const T* __restrict__ rv2,
    const T* __restrict__ w3, const T* __restrict__ b3,
    const T* __restrict__ g3, const T* __restrict__ be3,
    const T* __restrict__ rm3, const T* __restrict__ rv3,
    const T* __restrict__ w4, const T* __restrict__ b4,
    const T* __restrict__ wm, const T* __restrict__ bm,
    OT* __restrict__ out, const int* __restrict__ flag, const int want)
{
    if (flag[0] != want) return;   // wave-uniform path select

    // Weights pre-packed for v_pk_fma_f32: wpk[cin][o2] = {w[2o2][cin]*s,
    // w[2o2+1][cin]*s'} -> broadcast input scalar, accumulate output PAIRS.
    __shared__ __align__(16) f32x2 s_w1p[32][8];   // cin 0..15 nb | 16..31 ego
    __shared__ __align__(16) float s_b1[16];
    __shared__ __align__(16) f32x2 s_w2p[16][4];
    __shared__ __align__(16) float s_b2[8];
    __shared__ __align__(16) f32x2 s_w3p[8][2];
    __shared__ __align__(16) float s_b3[4];
    __shared__ __align__(16) float s_w4v[4];
    __shared__ float s_b4;
    __shared__ __align__(16) f32x2 s_wmp[16][8];
    __shared__ __align__(16) float s_bm[16];
    __shared__ float s_minv[L_AG][6];

    const int tid = threadIdx.x;

    // ---- block -> (ego, 2D tile), XCD-column + EGO-INNERMOST ordering ----
    const int bid      = blockIdx.x;
    const int tile_col = bid & 7;
    const int bp       = bid >> 3;        // 0..159
    const int i        = bp % L_AG;       // ego (inner)
    const int tile_row = bp / L_AG;       // 0..31 (outer)

    const int px_i = (tile_col << 5) + (tid & 31);   // 32x8 tile, coalesced rows
    const int py_i = (tile_row << 3) + (tid >> 5);
    const int p    = py_i * W_SZ + px_i;

    // ---- cooperative init: fold BN into conv weights, pack output-pairs ----
    {   // s_w1p: 32*8 = 256 entries, one per thread
        const int cin = tid >> 3, o2 = tid & 7;
        const int oa = 2 * o2, ob = 2 * o2 + 1;
        const float sa = ldf(g1 + oa) * rsqrtf(ldf(rv1 + oa) + 1e-5f);
        const float sb = ldf(g1 + ob) * rsqrtf(ldf(rv1 + ob) + 1e-5f);
        s_w1p[cin][o2] = (f32x2){ ldf(w1 + oa * 32 + cin) * sa,
                                  ldf(w1 + ob * 32 + cin) * sb };
    }
    if (tid < 64) {   // s_w2p: 16*4
        const int cin = tid >> 2, o2 = tid & 3;
        const int oa = 2 * o2, ob = 2 * o2 + 1;
        const float sa = ldf(g2 + oa) * rsqrtf(ldf(rv2 + oa) + 1e-5f);
        const float sb = ldf(g2 + ob) * rsqrtf(ldf(rv2 + ob) + 1e-5f);
        s_w2p[cin][o2] = (f32x2){ ldf(w2 + oa * 16 + cin) * sa,
                                  ldf(w2 + ob * 16 + cin) * sb };
    }
    if (tid < 16) {   // s_w3p: 8*2
        const int cin = tid >> 1, o2 = tid & 1;
        const int oa = 2 * o2, ob = 2 * o2 + 1;
        const float sa = ldf(g3 + oa) * rsqrtf(ldf(rv3 + oa) + 1e-5f);
        const float sb = ldf(g3 + ob) * rsqrtf(ldf(rv3 + ob) + 1e-5f);
        s_w3p[cin][o2] = (f32x2){ ldf(w3 + oa * 8 + cin) * sa,
                                  ldf(w3 + ob * 8 + cin) * sb };
    }
    if (tid >= 128 && tid < 256) {   // s_wmp: 16*8 (no BN fold)
        const int t = tid - 128;
        const int cin = t >> 3, o2 = t & 7;
        s_wmp[cin][o2] = (f32x2){ ldf(wm + (2 * o2) * 16 + cin),
                                  ldf(wm + (2 * o2 + 1) * 16 + cin) };
    }
    if (tid < 16) {
        const float s1 = ldf(g1 + tid) * rsqrtf(ldf(rv1 + tid) + 1e-5f);
        s_b1[tid] = (ldf(b1 + tid) - ldf(rm1 + tid)) * s1 + ldf(be1 + tid);
        s_bm[tid] = ldf(bm + tid);
    }
    if (tid < 8) {
        const float s2 = ldf(g2 + tid) * rsqrtf(ldf(rv2 + tid) + 1e-5f);
        s_b2[tid] = (ldf(b2 + tid) - ldf(rm2 + tid)) * s2 + ldf(be2 + tid);
    }
    if (tid < 4) {
        const float s3 = ldf(g3 + tid) * rsqrtf(ldf(rv3 + tid) + 1e-5f);
        s_b3[tid] = (ldf(b3 + tid) - ldf(rm3 + tid)) * s3 + ldf(be3 + tid);
        s_w4v[tid] = ldf(w4 + tid);
    }
    if (tid == 0) s_b4 = ldf(b4);

    if (tid < L_AG) {
        const int j = tid;
        const T* m = ptm + (j * L_AG + i) * 16;  // (1,L,L,4,4) row-major
        const float a  = ldf(m + 0);
        const float bb = ldf(m + 1);
        const float tx = ldf(m + 3) * 1.25f;     // / (0.4*2)
        const float c_ = ldf(m + 4);
        const float d  = ldf(m + 5);
        const float ty = ldf(m + 7) * 1.25f;
        float det = a * d - bb * c_;
        if (!(det > 1e-20f || det < -1e-20f)) det = 1.0f;  // guard: never Inf
        const float invdet = 1.0f / det;
        s_minv[j][0] =  d * invdet;
        s_minv[j][1] = -bb * invdet;
        s_minv[j][2] = (bb * ty - d * tx) * invdet;
        s_minv[j][3] = -c_ * invdet;
        s_minv[j][4] =  a * invdet;
        s_minv[j][5] = (c_ * tx - a * ty) * invdet;
    }
    __syncthreads();

    const float px = (float)px_i;
    const float py = (float)py_i;

    // ego contribution to layer 1 is j-invariant: hoist it (packed pairs).
    f32x2 h1bv[8];
#pragma unroll
    for (int o2 = 0; o2 < 8; ++o2)
        h1bv[o2] = *reinterpret_cast<const f32x2*>(&s_b1[2 * o2]);
    {
        const T* xp = x + i * C_CH * HW_SZ + p;
#pragma unroll
        for (int c = 0; c < C_CH; ++c) {
            const float e = ldf(xp + c * HW_SZ);
            const f32x2 bc = (f32x2){e, e};
#pragma unroll
            for (int o2 = 0; o2 < 8; ++o2)
                h1bv[o2] = pk_fma(s_w1p[16 + c][o2], bc, h1bv[o2]);
        }
    }

    float acc[C_CH];
#pragma unroll
    for (int c = 0; c < C_CH; ++c) acc[c] = 0.0f;
    float lsum = 0.0f;

    // ---- j-loop: serial row-phased taps (max 32 regs in flight), every
    // phase PINNED with sched_barrier(0) so the pre-RA scheduler cannot
    // hoist loads and inflate the live set past the cap (R9's bug). ----
#pragma unroll 1
    for (int j = 0; j < L_AG; ++j) {
        int po0, po1;
        float aw0, bw0, aw1, bw1;
        tap_params(s_minv, j, px, py, po0, po1, aw0, bw0, aw1, bw1);
        const T* img = x + j * C_CH * HW_SZ;

        float nb[C_CH];
        __builtin_amdgcn_sched_barrier(0);
        {   // phase 1: row y0 (16 addr-pairs fold +1 into offset imm)
            float tl[C_CH], th[C_CH];
#pragma unroll
            for (int c = 0; c < C_CH; ++c) {
                const T* ic = img + c * HW_SZ;
                tl[c] = ldf(ic + po0); th[c] = ldf(ic + po0 + 1);
            }
#pragma unroll
            for (int c = 0; c < C_CH; ++c) nb[c] = aw0 * tl[c] + bw0 * th[c];
        }
        __builtin_amdgcn_sched_barrier(0);
        {   // phase 2: row y1
            float tl[C_CH], th[C_CH];
#pragma unroll
            for (int c = 0; c < C_CH; ++c) {
                const T* ic = img + c * HW_SZ;
                tl[c] = ldf(ic + po1); th[c] = ldf(ic + po1 + 1);
            }
#pragma unroll
            for (int c = 0; c < C_CH; ++c) nb[c] += aw1 * tl[c] + bw1 * th[c];
        }
        __builtin_amdgcn_sched_barrier(0);

        // MLP 32->16->8->4->1, packed output-pairs (v_pk_fma_f32);
        // ego half of layer 1 precomputed in h1bv.
        f32x2 h1v[8];
#pragma unroll
        for (int o2 = 0; o2 < 8; ++o2) h1v[o2] = h1bv[o2];
#pragma unroll
        for (int c = 0; c < C_CH; ++c) {
            const f32x2 bc = (f32x2){nb[c], nb[c]};
#pragma unroll
            for (int o2 = 0; o2 < 8; ++o2)
                h1v[o2] = pk_fma(s_w1p[c][o2], bc, h1v[o2]);
        }
#pragma unroll
        for (int o2 = 0; o2 < 8; ++o2) h1v[o2] = pk_relu(h1v[o2]);

        f32x2 h2v[4];
#pragma unroll
        for (int o2 = 0; o2 < 4; ++o2)
            h2v[o2] = *reinterpret_cast<const f32x2*>(&s_b2[2 * o2]);
#pragma unroll
        for (int c = 0; c < 16; ++c) {
            const float hs = (c & 1) ? h1v[c >> 1].y : h1v[c >> 1].x;
            const f32x2 bc = (f32x2){hs, hs};
#pragma unroll
            for (int o2 = 0; o2 < 4; ++o2)
                h2v[o2] = pk_fma(s_w2p[c][o2], bc, h2v[o2]);
        }
#pragma unroll
        for (int o2 = 0; o2 < 4; ++o2) h2v[o2] = pk_relu(h2v[o2]);

        f32x2 h3v[2];
#pragma unroll
        for (int o2 = 0; o2 < 2; ++o2)
            h3v[o2] = *reinterpret_cast<const f32x2*>(&s_b3[2 * o2]);
#pragma unroll
        for (int c = 0; c < 8; ++c) {
            const float hs = (c & 1) ? h2v[c >> 1].y : h2v[c >> 1].x;
            const f32x2 bc = (f32x2){hs, hs};
#pragma unroll
            for (int o2 = 0; o2 < 2; ++o2)
                h3v[o2] = pk_fma(s_w3p[c][o2], bc, h3v[o2]);
        }
        h3v[0] = pk_relu(h3v[0]); h3v[1] = pk_relu(h3v[1]);

        float sc = s_b4 + s_w4v[0] * h3v[0].x + s_w4v[1] * h3v[0].y
                        + s_w4v[2] * h3v[1].x + s_w4v[3] * h3v[1].y;
        sc = fminf(fmaxf(sc, 0.0f), 60.0f);  // relu + overflow guard

        const float es = __expf(sc);
        lsum += es;
#pragma unroll
        for (int c = 0; c < C_CH; ++c) acc[c] += es * nb[c];
    }

    const float invl = 1.0f / lsum;
#pragma unroll
    for (int c = 0; c < C_CH; ++c) acc[c] *= invl;

    // epilogue: 16x16 mix, packed output-pairs
    f32x2 outv[8];
#pragma unroll
    for (int o2 = 0; o2 < 8; ++o2)
        outv[o2] = *reinterpret_cast<const f32x2*>(&s_bm[2 * o2]);
#pragma unroll
    for (int c = 0; c < C_CH; ++c) {
        const f32x2 bc = (f32x2){acc[c], acc[c]};
#pragma unroll
        for (int o2 = 0; o2 < 8; ++o2)
            outv[o2] = pk_fma(s_wmp[c][o2], bc, outv[o2]);
    }
    OT* op = out + i * C_CH * HW_SZ + p;
#pragma unroll
    for (int o2 = 0; o2 < 8; ++o2) {
        stf(op + (2 * o2) * HW_SZ,     outv[o2].x);
        stf(op + (2 * o2 + 1) * HW_SZ, outv[o2].y);
    }
}

extern "C" void kernel_launch(void* const* d_in, const int* in_sizes, int n_in,
                              void* d_out, int out_size, void* d_ws, size_t ws_size,
                              hipStream_t stream) {
    int* flag = (int*)d_ws;
    dtype_detect<<<1, 256, 0, stream>>>((const unsigned short*)d_in[0], flag);

    // 1280 blocks: 8 tile-cols x (5 egos inner x 32 tile-rows)
    dim3 grid(8 * 32 * L_AG);

    // bf16 path (flag==0)
    disconet_fused<bf16, bf16><<<grid, 256, 0, stream>>>(
        (const bf16*)d_in[0], (const bf16*)d_in[2],
        (const bf16*)d_in[3], (const bf16*)d_in[4],
        (const bf16*)d_in[5], (const bf16*)d_in[6],
        (const bf16*)d_in[7], (const bf16*)d_in[8],
        (const bf16*)d_in[9], (const bf16*)d_in[10],
        (const bf16*)d_in[11], (const bf16*)d_in[12],
        (const bf16*)d_in[13], (const bf16*)d_in[14],
        (const bf16*)d_in[15], (const bf16*)d_in[16],
        (const bf16*)d_in[17], (const bf16*)d_in[18],
        (const bf16*)d_in[19], (const bf16*)d_in[20],
        (const bf16*)d_in[21], (const bf16*)d_in[22],
        (const bf16*)d_in[23], (const bf16*)d_in[24],
        (bf16*)d_out, flag, 0);

    // fp32 path (flag==1)
    disconet_fused<float, float><<<grid, 256, 0, stream>>>(
        (const float*)d_in[0], (const float*)d_in[2],
        (const float*)d_in[3], (const float*)d_in[4],
        (const float*)d_in[5], (const float*)d_in[6],
        (const float*)d_in[7], (const float*)d_in[8],
        (const float*)d_in[9], (const float*)d_in[10],
        (const float*)d_in[11], (const float*)d_in[12],
        (const float*)d_in[13], (const float*)d_in[14],
        (const float*)d_in[15], (const float*)d_in[16],
        (const float*)d_in[17], (const float*)d_in[18],
        (const float*)d_in[19], (const float*)d_in[20],
        (const float*)d_in[21], (const float*)d_in[22],
        (const float*)d_in[23], (const float*)d_in[24],
        (float*)d_out, flag, 1);
}

// Round 14
// 158.045 us; speedup vs baseline: 1.3182x; 1.0823x over previous
//
#include <hip/hip_runtime.h>
#include <hip/hip_bf16.h>

typedef __hip_bfloat16 bf16;
typedef float f32x2 __attribute__((ext_vector_type(2)));

#define L_AG 5
#define C_CH 16
#define H_SZ 256
#define W_SZ 256
#define HW_SZ (H_SZ * W_SZ)

// dtype-polymorphic load/store helpers
__device__ __forceinline__ float ldf(const float* p) { return *p; }
__device__ __forceinline__ float ldf(const bf16* p)  { return __bfloat162float(*p); }
__device__ __forceinline__ void  stf(float* p, float v) { *p = v; }
__device__ __forceinline__ void  stf(bf16* p, float v)  { *p = __float2bfloat16(v); }

__device__ __forceinline__ f32x2 pk_fma(f32x2 a, f32x2 b, f32x2 c) {
    return __builtin_elementwise_fma(a, b, c);   // -> v_pk_fma_f32
}
__device__ __forceinline__ f32x2 pk_relu(f32x2 a) {
    return __builtin_elementwise_max(a, (f32x2){0.0f, 0.0f});  // -> v_pk_max_f32
}

// Inverse-affine taps for neighbor j as pair offsets (po0: row y0, po1: row
// y1, both at column base cx0p=min(cx0,W-2); the partner element is po+1)
// plus remapped bilinear weights (aw*lo + bw*hi per row). Exactly reproduces
// clamp+validity semantics.
__device__ __forceinline__ void tap_params(
    const float (*minv)[6], int j, float px, float py,
    int& po0, int& po1, float& aw0, float& bw0, float& aw1, float& bw1)
{
    const float m0 = minv[j][0], m1 = minv[j][1], m2 = minv[j][2];
    const float m3 = minv[j][3], m4 = minv[j][4], m5 = minv[j][5];
    const float sx = m0 * px + m1 * py + m2;
    const float sy = m3 * px + m4 * py + m5;
    const float fx0 = floorf(sx), fy0 = floorf(sy);
    const int x0 = (int)fx0, y0 = (int)fy0;
    const float wx1 = sx - fx0, wy1 = sy - fy0;
    const float wx0 = 1.0f - wx1, wy0 = 1.0f - wy1;
    const bool vx0 = (x0 >= 0) && (x0 <= W_SZ - 1);
    const bool vx1 = (x0 + 1 >= 0) && (x0 + 1 <= W_SZ - 1);
    const bool vy0 = (y0 >= 0) && (y0 <= H_SZ - 1);
    const bool vy1 = (y0 + 1 >= 0) && (y0 + 1 <= H_SZ - 1);
    const float w00 = (vx0 && vy0) ? wx0 * wy0 : 0.0f;
    const float w01 = (vx1 && vy0) ? wx1 * wy0 : 0.0f;
    const float w10 = (vx0 && vy1) ? wx0 * wy1 : 0.0f;
    const float w11 = (vx1 && vy1) ? wx1 * wy1 : 0.0f;
    const int cx0 = min(max(x0, 0), W_SZ - 1);
    const int cx1 = min(max(x0 + 1, 0), W_SZ - 1);
    const int cy0 = min(max(y0, 0), H_SZ - 1);
    const int cy1 = min(max(y0 + 1, 0), H_SZ - 1);
    const int cx0p = min(cx0, W_SZ - 2);
    const bool l0 = (cx0 == cx0p);   // does cx0 sit in the LO slot?
    const bool l1 = (cx1 == cx0p);   // does cx1 sit in the LO slot?
    aw0 = (l0 ? w00 : 0.0f) + (l1 ? w01 : 0.0f);
    bw0 = (l0 ? 0.0f : w00) + (l1 ? 0.0f : w01);
    aw1 = (l0 ? w10 : 0.0f) + (l1 ? w11 : 0.0f);
    bw1 = (l0 ? 0.0f : w10) + (l1 ? 0.0f : w11);
    po0 = cy0 * W_SZ + cx0p;
    po1 = cy1 * W_SZ + cx0p;
}

// R13's verified body (58.6 µs hot, VGPR 48, ~zero spill), unchanged.
template <typename T, typename OT>
__device__ __forceinline__ void run_body(
    const T* __restrict__ x, const T* __restrict__ ptm,
    const T* __restrict__ w1, const T* __restrict__ b1,
    const T* __restrict__ g1, const T* __restrict__ be1,
    const T* __restrict__ rm1, const T* __restrict__ rv1,
    const T* __restrict__ w2, const T* __restrict__ b2,
    const T* __restrict__ g2, const T* __restrict__ be2,
    const T* __restrict__ rm2, const T* __restrict__ rv2,
    const T* __restrict__ w3, const T* __restrict__ b3,
    const T* __restrict__ g3, const T* __restrict__ be3,
    const T* __restrict__ rm3, const T* __restrict__ rv3,
    const T* __restrict__ w4, const T* __restrict__ b4,
    const T* __restrict__ wm, const T* __restrict__ bm,
    OT* __restrict__ out, const int tid)
{
    // Weights pre-packed for v_pk_fma_f32: wpk[cin][o2] = {w[2o2][cin]*s,
    // w[2o2+1][cin]*s'} -> broadcast input scalar, accumulate output PAIRS.
    __shared__ __align__(16) f32x2 s_w1p[32][8];   // cin 0..15 nb | 16..31 ego
    __shared__ __align__(16) float s_b1[16];
    __shared__ __align__(16) f32x2 s_w2p[16][4];
    __shared__ __align__(16) float s_b2[8];
    __shared__ __align__(16) f32x2 s_w3p[8][2];
    __shared__ __align__(16) float s_b3[4];
    __shared__ __align__(16) float s_w4v[4];
    __shared__ float s_b4;
    __shared__ __align__(16) f32x2 s_wmp[16][8];
    __shared__ __align__(16) float s_bm[16];
    __shared__ float s_minv[L_AG][6];

    // ---- block -> (ego, 2D tile), XCD-column + EGO-INNERMOST ordering ----
    const int bid      = blockIdx.x;
    const int tile_col = bid & 7;
    const int bp       = bid >> 3;        // 0..159
    const int i        = bp % L_AG;       // ego (inner)
    const int tile_row = bp / L_AG;       // 0..31 (outer)

    const int px_i = (tile_col << 5) + (tid & 31);   // 32x8 tile, coalesced rows
    const int py_i = (tile_row << 3) + (tid >> 5);
    const int p    = py_i * W_SZ + px_i;

    // ---- cooperative init: fold BN into conv weights, pack output-pairs ----
    {   // s_w1p: 32*8 = 256 entries, one per thread
        const int cin = tid >> 3, o2 = tid & 7;
        const int oa = 2 * o2, ob = 2 * o2 + 1;
        const float sa = ldf(g1 + oa) * rsqrtf(ldf(rv1 + oa) + 1e-5f);
        const float sb = ldf(g1 + ob) * rsqrtf(ldf(rv1 + ob) + 1e-5f);
        s_w1p[cin][o2] = (f32x2){ ldf(w1 + oa * 32 + cin) * sa,
                                  ldf(w1 + ob * 32 + cin) * sb };
    }
    if (tid < 64) {   // s_w2p: 16*4
        const int cin = tid >> 2, o2 = tid & 3;
        const int oa = 2 * o2, ob = 2 * o2 + 1;
        const float sa = ldf(g2 + oa) * rsqrtf(ldf(rv2 + oa) + 1e-5f);
        const float sb = ldf(g2 + ob) * rsqrtf(ldf(rv2 + ob) + 1e-5f);
        s_w2p[cin][o2] = (f32x2){ ldf(w2 + oa * 16 + cin) * sa,
                                  ldf(w2 + ob * 16 + cin) * sb };
    }
    if (tid < 16) {   // s_w3p: 8*2
        const int cin = tid >> 1, o2 = tid & 1;
        const int oa = 2 * o2, ob = 2 * o2 + 1;
        const float sa = ldf(g3 + oa) * rsqrtf(ldf(rv3 + oa) + 1e-5f);
        const float sb = ldf(g3 + ob) * rsqrtf(ldf(rv3 + ob) + 1e-5f);
        s_w3p[cin][o2] = (f32x2){ ldf(w3 + oa * 8 + cin) * sa,
                                  ldf(w3 + ob * 8 + cin) * sb };
    }
    if (tid >= 128 && tid < 256) {   // s_wmp: 16*8 (no BN fold)
        const int t = tid - 128;
        const int cin = t >> 3, o2 = t & 7;
        s_wmp[cin][o2] = (f32x2){ ldf(wm + (2 * o2) * 16 + cin),
                                  ldf(wm + (2 * o2 + 1) * 16 + cin) };
    }
    if (tid < 16) {
        const float s1 = ldf(g1 + tid) * rsqrtf(ldf(rv1 + tid) + 1e-5f);
        s_b1[tid] = (ldf(b1 + tid) - ldf(rm1 + tid)) * s1 + ldf(be1 + tid);
        s_bm[tid] = ldf(bm + tid);
    }
    if (tid < 8) {
        const float s2 = ldf(g2 + tid) * rsqrtf(ldf(rv2 + tid) + 1e-5f);
        s_b2[tid] = (ldf(b2 + tid) - ldf(rm2 + tid)) * s2 + ldf(be2 + tid);
    }
    if (tid < 4) {
        const float s3 = ldf(g3 + tid) * rsqrtf(ldf(rv3 + tid) + 1e-5f);
        s_b3[tid] = (ldf(b3 + tid) - ldf(rm3 + tid)) * s3 + ldf(be3 + tid);
        s_w4v[tid] = ldf(w4 + tid);
    }
    if (tid == 0) s_b4 = ldf(b4);

    if (tid < L_AG) {
        const int j = tid;
        const T* m = ptm + (j * L_AG + i) * 16;  // (1,L,L,4,4) row-major
        const float a  = ldf(m + 0);
        const float bb = ldf(m + 1);
        const float tx = ldf(m + 3) * 1.25f;     // / (0.4*2)
        const float c_ = ldf(m + 4);
        const float d  = ldf(m + 5);
        const float ty = ldf(m + 7) * 1.25f;
        float det = a * d - bb * c_;
        if (!(det > 1e-20f || det < -1e-20f)) det = 1.0f;  // guard: never Inf
        const float invdet = 1.0f / det;
        s_minv[j][0] =  d * invdet;
        s_minv[j][1] = -bb * invdet;
        s_minv[j][2] = (bb * ty - d * tx) * invdet;
        s_minv[j][3] = -c_ * invdet;
        s_minv[j][4] =  a * invdet;
        s_minv[j][5] = (c_ * tx - a * ty) * invdet;
    }
    __syncthreads();

    const float px = (float)px_i;
    const float py = (float)py_i;

    // ego contribution to layer 1 is j-invariant: hoist it (packed pairs).
    f32x2 h1bv[8];
#pragma unroll
    for (int o2 = 0; o2 < 8; ++o2)
        h1bv[o2] = *reinterpret_cast<const f32x2*>(&s_b1[2 * o2]);
    {
        const T* xp = x + i * C_CH * HW_SZ + p;
#pragma unroll
        for (int c = 0; c < C_CH; ++c) {
            const float e = ldf(xp + c * HW_SZ);
            const f32x2 bc = (f32x2){e, e};
#pragma unroll
            for (int o2 = 0; o2 < 8; ++o2)
                h1bv[o2] = pk_fma(s_w1p[16 + c][o2], bc, h1bv[o2]);
        }
    }

    float acc[C_CH];
#pragma unroll
    for (int c = 0; c < C_CH; ++c) acc[c] = 0.0f;
    float lsum = 0.0f;

    // ---- j-loop: serial row-phased taps (max 32 regs in flight), every
    // phase PINNED with sched_barrier(0) so the pre-RA scheduler cannot
    // hoist loads and inflate the live set past the cap (R9's bug). ----
#pragma unroll 1
    for (int j = 0; j < L_AG; ++j) {
        int po0, po1;
        float aw0, bw0, aw1, bw1;
        tap_params(s_minv, j, px, py, po0, po1, aw0, bw0, aw1, bw1);
        const T* img = x + j * C_CH * HW_SZ;

        float nb[C_CH];
        __builtin_amdgcn_sched_barrier(0);
        {   // phase 1: row y0 (16 addr-pairs fold +1 into offset imm)
            float tl[C_CH], th[C_CH];
#pragma unroll
            for (int c = 0; c < C_CH; ++c) {
                const T* ic = img + c * HW_SZ;
                tl[c] = ldf(ic + po0); th[c] = ldf(ic + po0 + 1);
            }
#pragma unroll
            for (int c = 0; c < C_CH; ++c) nb[c] = aw0 * tl[c] + bw0 * th[c];
        }
        __builtin_amdgcn_sched_barrier(0);
        {   // phase 2: row y1
            float tl[C_CH], th[C_CH];
#pragma unroll
            for (int c = 0; c < C_CH; ++c) {
                const T* ic = img + c * HW_SZ;
                tl[c] = ldf(ic + po1); th[c] = ldf(ic + po1 + 1);
            }
#pragma unroll
            for (int c = 0; c < C_CH; ++c) nb[c] += aw1 * tl[c] + bw1 * th[c];
        }
        __builtin_amdgcn_sched_barrier(0);

        // MLP 32->16->8->4->1, packed output-pairs (v_pk_fma_f32);
        // ego half of layer 1 precomputed in h1bv.
        f32x2 h1v[8];
#pragma unroll
        for (int o2 = 0; o2 < 8; ++o2) h1v[o2] = h1bv[o2];
#pragma unroll
        for (int c = 0; c < C_CH; ++c) {
            const f32x2 bc = (f32x2){nb[c], nb[c]};
#pragma unroll
            for (int o2 = 0; o2 < 8; ++o2)
                h1v[o2] = pk_fma(s_w1p[c][o2], bc, h1v[o2]);
        }
#pragma unroll
        for (int o2 = 0; o2 < 8; ++o2) h1v[o2] = pk_relu(h1v[o2]);

        f32x2 h2v[4];
#pragma unroll
        for (int o2 = 0; o2 < 4; ++o2)
            h2v[o2] = *reinterpret_cast<const f32x2*>(&s_b2[2 * o2]);
#pragma unroll
        for (int c = 0; c < 16; ++c) {
            const float hs = (c & 1) ? h1v[c >> 1].y : h1v[c >> 1].x;
            const f32x2 bc = (f32x2){hs, hs};
#pragma unroll
            for (int o2 = 0; o2 < 4; ++o2)
                h2v[o2] = pk_fma(s_w2p[c][o2], bc, h2v[o2]);
        }
#pragma unroll
        for (int o2 = 0; o2 < 4; ++o2) h2v[o2] = pk_relu(h2v[o2]);

        f32x2 h3v[2];
#pragma unroll
        for (int o2 = 0; o2 < 2; ++o2)
            h3v[o2] = *reinterpret_cast<const f32x2*>(&s_b3[2 * o2]);
#pragma unroll
        for (int c = 0; c < 8; ++c) {
            const float hs = (c & 1) ? h2v[c >> 1].y : h2v[c >> 1].x;
            const f32x2 bc = (f32x2){hs, hs};
#pragma unroll
            for (int o2 = 0; o2 < 2; ++o2)
                h3v[o2] = pk_fma(s_w3p[c][o2], bc, h3v[o2]);
        }
        h3v[0] = pk_relu(h3v[0]); h3v[1] = pk_relu(h3v[1]);

        float sc = s_b4 + s_w4v[0] * h3v[0].x + s_w4v[1] * h3v[0].y
                        + s_w4v[2] * h3v[1].x + s_w4v[3] * h3v[1].y;
        sc = fminf(fmaxf(sc, 0.0f), 60.0f);  // relu + overflow guard

        const float es = __expf(sc);
        lsum += es;
#pragma unroll
        for (int c = 0; c < C_CH; ++c) acc[c] += es * nb[c];
    }

    const float invl = 1.0f / lsum;
#pragma unroll
    for (int c = 0; c < C_CH; ++c) acc[c] *= invl;

    // epilogue: 16x16 mix, packed output-pairs
    f32x2 outv[8];
#pragma unroll
    for (int o2 = 0; o2 < 8; ++o2)
        outv[o2] = *reinterpret_cast<const f32x2*>(&s_bm[2 * o2]);
#pragma unroll
    for (int c = 0; c < C_CH; ++c) {
        const f32x2 bc = (f32x2){acc[c], acc[c]};
#pragma unroll
        for (int o2 = 0; o2 < 8; ++o2)
            outv[o2] = pk_fma(s_wmp[c][o2], bc, outv[o2]);
    }
    OT* op = out + i * C_CH * HW_SZ + p;
#pragma unroll
    for (int o2 = 0; o2 < 8; ++o2) {
        stf(op + (2 * o2) * HW_SZ,     outv[o2].x);
        stf(op + (2 * o2 + 1) * HW_SZ, outv[o2].y);
    }
}

// Single launch: each block self-detects dtype from the first 2KB of x
// (bf16 ~N(0,1): exponent field < 0x90 always; fp32 mantissa words ~43%
// have exp>=0x90), then takes a block-uniform typed path. Removes the
// detect-kernel + dead-template launches (3 -> 1 per iteration).
__global__ __launch_bounds__(256, 5) void disconet_one(
    const void* __restrict__ x, const void* __restrict__ ptm,
    const void* __restrict__ w1, const void* __restrict__ b1,
    const void* __restrict__ g1, const void* __restrict__ be1,
    const void* __restrict__ rm1, const void* __restrict__ rv1,
    const void* __restrict__ w2, const void* __restrict__ b2,
    const void* __restrict__ g2, const void* __restrict__ be2,
    const void* __restrict__ rm2, const void* __restrict__ rv2,
    const void* __restrict__ w3, const void* __restrict__ b3,
    const void* __restrict__ g3, const void* __restrict__ be3,
    const void* __restrict__ rm3, const void* __restrict__ rv3,
    const void* __restrict__ w4, const void* __restrict__ b4,
    const void* __restrict__ wm, const void* __restrict__ bm,
    void* __restrict__ out)
{
    const int tid = threadIdx.x;
    __shared__ int s_flag;
    if (tid == 0) s_flag = 0;
    __syncthreads();
    {
        const unsigned short* xw = (const unsigned short*)x;
        int h = 0;
        for (int t = tid; t < 512; t += 256) {
            const unsigned short w = xw[2 * t];
            h += (((w >> 7) & 0xFF) >= 0x90) ? 1 : 0;
        }
        if (h) atomicAdd(&s_flag, h);
    }
    __syncthreads();
    const bool is_fp32 = (s_flag >= 16);  // block-uniform

    if (is_fp32) {
        run_body<float, float>(
            (const float*)x, (const float*)ptm,
            (const float*)w1, (const float*)b1, (const float*)g1, (const float*)be1,
            (const float*)rm1, (const float*)rv1,
            (const float*)w2, (const float*)b2, (const float*)g2, (const float*)be2,
            (const float*)rm2, (const float*)rv2,
            (const float*)w3, (const float*)b3, (const float*)g3, (const float*)be3,
            (const float*)rm3, (const float*)rv3,
            (const float*)w4, (const float*)b4, (const float*)wm, (const float*)bm,
            (float*)out, tid);
    } else {
        run_body<bf16, bf16>(
            (const bf16*)x, (const bf16*)ptm,
            (const bf16*)w1, (const bf16*)b1, (const bf16*)g1, (const bf16*)be1,
            (const bf16*)rm1, (const bf16*)rv1,
            (const bf16*)w2, (const bf16*)b2, (const bf16*)g2, (const bf16*)be2,
            (const bf16*)rm2, (const bf16*)rv2,
            (const bf16*)w3, (const bf16*)b3, (const bf16*)g3, (const bf16*)be3,
            (const bf16*)rm3, (const bf16*)rv3,
            (const bf16*)w4, (const bf16*)b4, (const bf16*)wm, (const bf16*)bm,
            (bf16*)out, tid);
    }
}

extern "C" void kernel_launch(void* const* d_in, const int* in_sizes, int n_in,
                              void* d_out, int out_size, void* d_ws, size_t ws_size,
                              hipStream_t stream) {
    // 1280 blocks: 8 tile-cols x (5 egos inner x 32 tile-rows)
    dim3 grid(8 * 32 * L_AG);
    disconet_one<<<grid, 256, 0, stream>>>(
        d_in[0], d_in[2],
        d_in[3], d_in[4], d_in[5], d_in[6], d_in[7], d_in[8],
        d_in[9], d_in[10], d_in[11], d_in[12], d_in[13], d_in[14],
        d_in[15], d_in[16], d_in[17], d_in[18], d_in[19], d_in[20],
        d_in[21], d_in[22], d_in[23], d_in[24],
        d_out);
}

// Round 16
// 157.243 us; speedup vs baseline: 1.3249x; 1.0051x over previous
//
#include <hip/hip_runtime.h>
#include <hip/hip_bf16.h>

typedef __hip_bfloat16 bf16;
typedef float f32x2 __attribute__((ext_vector_type(2)));

#define L_AG 5
#define C_CH 16
#define H_SZ 256
#define W_SZ 256
#define HW_SZ (H_SZ * W_SZ)

// dtype-polymorphic load/store helpers
__device__ __forceinline__ float ldf(const float* p) { return *p; }
__device__ __forceinline__ float ldf(const bf16* p)  { return __bfloat162float(*p); }
__device__ __forceinline__ void  stf(float* p, float v) { *p = v; }
__device__ __forceinline__ void  stf(bf16* p, float v)  { *p = __float2bfloat16(v); }

__device__ __forceinline__ f32x2 pk_fma(f32x2 a, f32x2 b, f32x2 c) {
    return __builtin_elementwise_fma(a, b, c);   // -> v_pk_fma_f32
}
__device__ __forceinline__ f32x2 pk_relu(f32x2 a) {
    return __builtin_elementwise_max(a, (f32x2){0.0f, 0.0f});  // -> v_pk_max_f32
}

// Inverse-affine taps for neighbor j as pair offsets (po0: row y0, po1: row
// y1, both at column base cx0p=min(cx0,W-2); the partner element is po+1)
// plus remapped bilinear weights (aw*lo + bw*hi per row). Exactly reproduces
// clamp+validity semantics.
__device__ __forceinline__ void tap_params(
    const float (*minv)[6], int j, float px, float py,
    int& po0, int& po1, float& aw0, float& bw0, float& aw1, float& bw1)
{
    const float m0 = minv[j][0], m1 = minv[j][1], m2 = minv[j][2];
    const float m3 = minv[j][3], m4 = minv[j][4], m5 = minv[j][5];
    const float sx = m0 * px + m1 * py + m2;
    const float sy = m3 * px + m4 * py + m5;
    const float fx0 = floorf(sx), fy0 = floorf(sy);
    const int x0 = (int)fx0, y0 = (int)fy0;
    const float wx1 = sx - fx0, wy1 = sy - fy0;
    const float wx0 = 1.0f - wx1, wy0 = 1.0f - wy1;
    const bool vx0 = (x0 >= 0) && (x0 <= W_SZ - 1);
    const bool vx1 = (x0 + 1 >= 0) && (x0 + 1 <= W_SZ - 1);
    const bool vy0 = (y0 >= 0) && (y0 <= H_SZ - 1);
    const bool vy1 = (y0 + 1 >= 0) && (y0 + 1 <= H_SZ - 1);
    const float w00 = (vx0 && vy0) ? wx0 * wy0 : 0.0f;
    const float w01 = (vx1 && vy0) ? wx1 * wy0 : 0.0f;
    const float w10 = (vx0 && vy1) ? wx0 * wy1 : 0.0f;
    const float w11 = (vx1 && vy1) ? wx1 * wy1 : 0.0f;
    const int cx0 = min(max(x0, 0), W_SZ - 1);
    const int cx1 = min(max(x0 + 1, 0), W_SZ - 1);
    const int cy0 = min(max(y0, 0), H_SZ - 1);
    const int cy1 = min(max(y0 + 1, 0), H_SZ - 1);
    const int cx0p = min(cx0, W_SZ - 2);
    const bool l0 = (cx0 == cx0p);   // does cx0 sit in the LO slot?
    const bool l1 = (cx1 == cx0p);   // does cx1 sit in the LO slot?
    aw0 = (l0 ? w00 : 0.0f) + (l1 ? w01 : 0.0f);
    bw0 = (l0 ? 0.0f : w00) + (l1 ? 0.0f : w01);
    aw1 = (l0 ? w10 : 0.0f) + (l1 ? w11 : 0.0f);
    bw1 = (l0 ? 0.0f : w10) + (l1 ? 0.0f : w11);
    po0 = cy0 * W_SZ + cx0p;
    po1 = cy1 * W_SZ + cx0p;
}

// R14 body with ONE change: the two row phases' loads are issued together
// (64 in flight), then combined — compiler emits counted vmcnt waits so
// row-0 combines overlap row-1 returns. Stalls per j: 2 -> ~1. Taps still
// die at the combine (never live across the MLP); fences prevent cross-j
// hoisting per R10-R14. Cap 102 (promise 5). (Resubmission of R15 — infra
// flake, no counters; precedent R10->R11.)
template <typename T, typename OT>
__device__ __forceinline__ void run_body(
    const T* __restrict__ x, const T* __restrict__ ptm,
    const T* __restrict__ w1, const T* __restrict__ b1,
    const T* __restrict__ g1, const T* __restrict__ be1,
    const T* __restrict__ rm1, const T* __restrict__ rv1,
    const T* __restrict__ w2, const T* __restrict__ b2,
    const T* __restrict__ g2, const T* __restrict__ be2,
    const T* __restrict__ rm2, const T* __restrict__ rv2,
    const T* __restrict__ w3, const T* __restrict__ b3,
    const T* __restrict__ g3, const T* __restrict__ be3,
    const T* __restrict__ rm3, const T* __restrict__ rv3,
    const T* __restrict__ w4, const T* __restrict__ b4,
    const T* __restrict__ wm, const T* __restrict__ bm,
    OT* __restrict__ out, const int tid)
{
    // Weights pre-packed for v_pk_fma_f32: wpk[cin][o2] = {w[2o2][cin]*s,
    // w[2o2+1][cin]*s'} -> broadcast input scalar, accumulate output PAIRS.
    __shared__ __align__(16) f32x2 s_w1p[32][8];   // cin 0..15 nb | 16..31 ego
    __shared__ __align__(16) float s_b1[16];
    __shared__ __align__(16) f32x2 s_w2p[16][4];
    __shared__ __align__(16) float s_b2[8];
    __shared__ __align__(16) f32x2 s_w3p[8][2];
    __shared__ __align__(16) float s_b3[4];
    __shared__ __align__(16) float s_w4v[4];
    __shared__ float s_b4;
    __shared__ __align__(16) f32x2 s_wmp[16][8];
    __shared__ __align__(16) float s_bm[16];
    __shared__ float s_minv[L_AG][6];

    // ---- block -> (ego, 2D tile), XCD-column + EGO-INNERMOST ordering ----
    const int bid      = blockIdx.x;
    const int tile_col = bid & 7;
    const int bp       = bid >> 3;        // 0..159
    const int i        = bp % L_AG;       // ego (inner)
    const int tile_row = bp / L_AG;       // 0..31 (outer)

    const int px_i = (tile_col << 5) + (tid & 31);   // 32x8 tile, coalesced rows
    const int py_i = (tile_row << 3) + (tid >> 5);
    const int p    = py_i * W_SZ + px_i;

    // ---- cooperative init: fold BN into conv weights, pack output-pairs ----
    {   // s_w1p: 32*8 = 256 entries, one per thread
        const int cin = tid >> 3, o2 = tid & 7;
        const int oa = 2 * o2, ob = 2 * o2 + 1;
        const float sa = ldf(g1 + oa) * rsqrtf(ldf(rv1 + oa) + 1e-5f);
        const float sb = ldf(g1 + ob) * rsqrtf(ldf(rv1 + ob) + 1e-5f);
        s_w1p[cin][o2] = (f32x2){ ldf(w1 + oa * 32 + cin) * sa,
                                  ldf(w1 + ob * 32 + cin) * sb };
    }
    if (tid < 64) {   // s_w2p: 16*4
        const int cin = tid >> 2, o2 = tid & 3;
        const int oa = 2 * o2, ob = 2 * o2 + 1;
        const float sa = ldf(g2 + oa) * rsqrtf(ldf(rv2 + oa) + 1e-5f);
        const float sb = ldf(g2 + ob) * rsqrtf(ldf(rv2 + ob) + 1e-5f);
        s_w2p[cin][o2] = (f32x2){ ldf(w2 + oa * 16 + cin) * sa,
                                  ldf(w2 + ob * 16 + cin) * sb };
    }
    if (tid < 16) {   // s_w3p: 8*2
        const int cin = tid >> 1, o2 = tid & 1;
        const int oa = 2 * o2, ob = 2 * o2 + 1;
        const float sa = ldf(g3 + oa) * rsqrtf(ldf(rv3 + oa) + 1e-5f);
        const float sb = ldf(g3 + ob) * rsqrtf(ldf(rv3 + ob) + 1e-5f);
        s_w3p[cin][o2] = (f32x2){ ldf(w3 + oa * 8 + cin) * sa,
                                  ldf(w3 + ob * 8 + cin) * sb };
    }
    if (tid >= 128 && tid < 256) {   // s_wmp: 16*8 (no BN fold)
        const int t = tid - 128;
        const int cin = t >> 3, o2 = t & 7;
        s_wmp[cin][o2] = (f32x2){ ldf(wm + (2 * o2) * 16 + cin),
                                  ldf(wm + (2 * o2 + 1) * 16 + cin) };
    }
    if (tid < 16) {
        const float s1 = ldf(g1 + tid) * rsqrtf(ldf(rv1 + tid) + 1e-5f);
        s_b1[tid] = (ldf(b1 + tid) - ldf(rm1 + tid)) * s1 + ldf(be1 + tid);
        s_bm[tid] = ldf(bm + tid);
    }
    if (tid < 8) {
        const float s2 = ldf(g2 + tid) * rsqrtf(ldf(rv2 + tid) + 1e-5f);
        s_b2[tid] = (ldf(b2 + tid) - ldf(rm2 + tid)) * s2 + ldf(be2 + tid);
    }
    if (tid < 4) {
        const float s3 = ldf(g3 + tid) * rsqrtf(ldf(rv3 + tid) + 1e-5f);
        s_b3[tid] = (ldf(b3 + tid) - ldf(rm3 + tid)) * s3 + ldf(be3 + tid);
        s_w4v[tid] = ldf(w4 + tid);
    }
    if (tid == 0) s_b4 = ldf(b4);

    if (tid < L_AG) {
        const int j = tid;
        const T* m = ptm + (j * L_AG + i) * 16;  // (1,L,L,4,4) row-major
        const float a  = ldf(m + 0);
        const float bb = ldf(m + 1);
        const float tx = ldf(m + 3) * 1.25f;     // / (0.4*2)
        const float c_ = ldf(m + 4);
        const float d  = ldf(m + 5);
        const float ty = ldf(m + 7) * 1.25f;
        float det = a * d - bb * c_;
        if (!(det > 1e-20f || det < -1e-20f)) det = 1.0f;  // guard: never Inf
        const float invdet = 1.0f / det;
        s_minv[j][0] =  d * invdet;
        s_minv[j][1] = -bb * invdet;
        s_minv[j][2] = (bb * ty - d * tx) * invdet;
        s_minv[j][3] = -c_ * invdet;
        s_minv[j][4] =  a * invdet;
        s_minv[j][5] = (c_ * tx - a * ty) * invdet;
    }
    __syncthreads();

    const float px = (float)px_i;
    const float py = (float)py_i;

    // ego contribution to layer 1 is j-invariant: hoist it (packed pairs).
    f32x2 h1bv[8];
#pragma unroll
    for (int o2 = 0; o2 < 8; ++o2)
        h1bv[o2] = *reinterpret_cast<const f32x2*>(&s_b1[2 * o2]);
    {
        const T* xp = x + i * C_CH * HW_SZ + p;
#pragma unroll
        for (int c = 0; c < C_CH; ++c) {
            const float e = ldf(xp + c * HW_SZ);
            const f32x2 bc = (f32x2){e, e};
#pragma unroll
            for (int o2 = 0; o2 < 8; ++o2)
                h1bv[o2] = pk_fma(s_w1p[16 + c][o2], bc, h1bv[o2]);
        }
    }

    float acc[C_CH];
#pragma unroll
    for (int c = 0; c < C_CH; ++c) acc[c] = 0.0f;
    float lsum = 0.0f;

    // ---- j-loop: FUSED row phases — all 64 tap loads issued before any
    // combine (counted vmcnt overlap), taps die at the combine. Fences pin
    // issue/combine/MLP boundaries so cross-j hoisting can't inflate the
    // live set (R9's bug). ----
#pragma unroll 1
    for (int j = 0; j < L_AG; ++j) {
        int po0, po1;
        float aw0, bw0, aw1, bw1;
        tap_params(s_minv, j, px, py, po0, po1, aw0, bw0, aw1, bw1);
        const T* img = x + j * C_CH * HW_SZ;

        float tl0[C_CH], th0[C_CH], tl1[C_CH], th1[C_CH];
        __builtin_amdgcn_sched_barrier(0);
#pragma unroll
        for (int c = 0; c < C_CH; ++c) {   // row y0 (po+1 folds to offset imm)
            const T* ic = img + c * HW_SZ;
            tl0[c] = ldf(ic + po0); th0[c] = ldf(ic + po0 + 1);
        }
#pragma unroll
        for (int c = 0; c < C_CH; ++c) {   // row y1, issued before y0 drains
            const T* ic = img + c * HW_SZ;
            tl1[c] = ldf(ic + po1); th1[c] = ldf(ic + po1 + 1);
        }
        __builtin_amdgcn_sched_barrier(0);
        float nb[C_CH];
#pragma unroll
        for (int c = 0; c < C_CH; ++c)
            nb[c] = aw0 * tl0[c] + bw0 * th0[c] +
                    aw1 * tl1[c] + bw1 * th1[c];
        __builtin_amdgcn_sched_barrier(0);

        // MLP 32->16->8->4->1, packed output-pairs (v_pk_fma_f32);
        // ego half of layer 1 precomputed in h1bv.
        f32x2 h1v[8];
#pragma unroll
        for (int o2 = 0; o2 < 8; ++o2) h1v[o2] = h1bv[o2];
#pragma unroll
        for (int c = 0; c < C_CH; ++c) {
            const f32x2 bc = (f32x2){nb[c], nb[c]};
#pragma unroll
            for (int o2 = 0; o2 < 8; ++o2)
                h1v[o2] = pk_fma(s_w1p[c][o2], bc, h1v[o2]);
        }
#pragma unroll
        for (int o2 = 0; o2 < 8; ++o2) h1v[o2] = pk_relu(h1v[o2]);

        f32x2 h2v[4];
#pragma unroll
        for (int o2 = 0; o2 < 4; ++o2)
            h2v[o2] = *reinterpret_cast<const f32x2*>(&s_b2[2 * o2]);
#pragma unroll
        for (int c = 0; c < 16; ++c) {
            const float hs = (c & 1) ? h1v[c >> 1].y : h1v[c >> 1].x;
            const f32x2 bc = (f32x2){hs, hs};
#pragma unroll
            for (int o2 = 0; o2 < 4; ++o2)
                h2v[o2] = pk_fma(s_w2p[c][o2], bc, h2v[o2]);
        }
#pragma unroll
        for (int o2 = 0; o2 < 4; ++o2) h2v[o2] = pk_relu(h2v[o2]);

        f32x2 h3v[2];
#pragma unroll
        for (int o2 = 0; o2 < 2; ++o2)
            h3v[o2] = *reinterpret_cast<const f32x2*>(&s_b3[2 * o2]);
#pragma unroll
        for (int c = 0; c < 8; ++c) {
            const float hs = (c & 1) ? h2v[c >> 1].y : h2v[c >> 1].x;
            const f32x2 bc = (f32x2){hs, hs};
#pragma unroll
            for (int o2 = 0; o2 < 2; ++o2)
                h3v[o2] = pk_fma(s_w3p[c][o2], bc, h3v[o2]);
        }
        h3v[0] = pk_relu(h3v[0]); h3v[1] = pk_relu(h3v[1]);

        float sc = s_b4 + s_w4v[0] * h3v[0].x + s_w4v[1] * h3v[0].y
                        + s_w4v[2] * h3v[1].x + s_w4v[3] * h3v[1].y;
        sc = fminf(fmaxf(sc, 0.0f), 60.0f);  // relu + overflow guard

        const float es = __expf(sc);
        lsum += es;
#pragma unroll
        for (int c = 0; c < C_CH; ++c) acc[c] += es * nb[c];
    }

    const float invl = 1.0f / lsum;
#pragma unroll
    for (int c = 0; c < C_CH; ++c) acc[c] *= invl;

    // epilogue: 16x16 mix, packed output-pairs
    f32x2 outv[8];
#pragma unroll
    for (int o2 = 0; o2 < 8; ++o2)
        outv[o2] = *reinterpret_cast<const f32x2*>(&s_bm[2 * o2]);
#pragma unroll
    for (int c = 0; c < C_CH; ++c) {
        const f32x2 bc = (f32x2){acc[c], acc[c]};
#pragma unroll
        for (int o2 = 0; o2 < 8; ++o2)
            outv[o2] = pk_fma(s_wmp[c][o2], bc, outv[o2]);
    }
    OT* op = out + i * C_CH * HW_SZ + p;
#pragma unroll
    for (int o2 = 0; o2 < 8; ++o2) {
        stf(op + (2 * o2) * HW_SZ,     outv[o2].x);
        stf(op + (2 * o2 + 1) * HW_SZ, outv[o2].y);
    }
}

// Single launch: each block self-detects dtype from the first 2KB of x
// (bf16 ~N(0,1): exponent field < 0x90 always; fp32 mantissa words ~43%
// have exp>=0x90), then takes a block-uniform typed path.
__global__ __launch_bounds__(256, 5) void disconet_one(
    const void* __restrict__ x, const void* __restrict__ ptm,
    const void* __restrict__ w1, const void* __restrict__ b1,
    const void* __restrict__ g1, const void* __restrict__ be1,
    const void* __restrict__ rm1, const void* __restrict__ rv1,
    const void* __restrict__ w2, const void* __restrict__ b2,
    const void* __restrict__ g2, const void* __restrict__ be2,
    const void* __restrict__ rm2, const void* __restrict__ rv2,
    const void* __restrict__ w3, const void* __restrict__ b3,
    const void* __restrict__ g3, const void* __restrict__ be3,
    const void* __restrict__ rm3, const void* __restrict__ rv3,
    const void* __restrict__ w4, const void* __restrict__ b4,
    const void* __restrict__ wm, const void* __restrict__ bm,
    void* __restrict__ out)
{
    const int tid = threadIdx.x;
    __shared__ int s_flag;
    if (tid == 0) s_flag = 0;
    __syncthreads();
    {
        const unsigned short* xw = (const unsigned short*)x;
        int h = 0;
        for (int t = tid; t < 512; t += 256) {
            const unsigned short w = xw[2 * t];
            h += (((w >> 7) & 0xFF) >= 0x90) ? 1 : 0;
        }
        if (h) atomicAdd(&s_flag, h);
    }
    __syncthreads();
    const bool is_fp32 = (s_flag >= 16);  // block-uniform

    if (is_fp32) {
        run_body<float, float>(
            (const float*)x, (const float*)ptm,
            (const float*)w1, (const float*)b1, (const float*)g1, (const float*)be1,
            (const float*)rm1, (const float*)rv1,
            (const float*)w2, (const float*)b2, (const float*)g2, (const float*)be2,
            (const float*)rm2, (const float*)rv2,
            (const float*)w3, (const float*)b3, (const float*)g3, (const float*)be3,
            (const float*)rm3, (const float*)rv3,
            (const float*)w4, (const float*)b4, (const float*)wm, (const float*)bm,
            (float*)out, tid);
    } else {
        run_body<bf16, bf16>(
            (const bf16*)x, (const bf16*)ptm,
            (const bf16*)w1, (const bf16*)b1, (const bf16*)g1, (const bf16*)be1,
            (const bf16*)rm1, (const bf16*)rv1,
            (const bf16*)w2, (const bf16*)b2, (const bf16*)g2, (const bf16*)be2,
            (const bf16*)rm2, (const bf16*)rv2,
            (const bf16*)w3, (const bf16*)b3, (const bf16*)g3, (const bf16*)be3,
            (const bf16*)rm3, (const bf16*)rv3,
            (const bf16*)w4, (const bf16*)b4, (const bf16*)wm, (const bf16*)bm,
            (bf16*)out, tid);
    }
}

extern "C" void kernel_launch(void* const* d_in, const int* in_sizes, int n_in,
                              void* d_out, int out_size, void* d_ws, size_t ws_size,
                              hipStream_t stream) {
    // 1280 blocks: 8 tile-cols x (5 egos inner x 32 tile-rows)
    dim3 grid(8 * 32 * L_AG);
    disconet_one<<<grid, 256, 0, stream>>>(
        d_in[0], d_in[2],
        d_in[3], d_in[4], d_in[5], d_in[6], d_in[7], d_in[8],
        d_in[9], d_in[10], d_in[11], d_in[12], d_in[13], d_in[14],
        d_in[15], d_in[16], d_in[17], d_in[18], d_in[19], d_in[20],
        d_in[21], d_in[22], d_in[23], d_in[24],
        d_out);
}